// Round 12
// baseline (511.595 us; speedup 1.0000x reference)
//
#include <hip/hip_runtime.h>
#include <math.h>

// ---------------------------------------------------------------------------
// N2V GCN edge model, fp32.
//   CSR build: cnt=indeg(dst); dinv=rsqrt(cnt+1); rp=exscan; srcs+coefs bucketed
//   L1: A = x@W1 ; B = relu(gatherCSR(A) + A*dinv^2 + b1)
//   L2: A = B@W2 ; B = relu(gatherCSR(A) + A*dinv^2 + b2)
//   head: per pair: feat=[u,v,|u-v|,u*v]; z=relu(feat@M1+mb1); out=z@M2+mb2
// Round-12: tail reverted to round-10 exactly (round-11's padded gather +
// factorization was neutral-to-worse; tail noise band ~±15us).
// Head: M1 moved from s_load to VMEM broadcast loads with an explicit
// register double-buffer (named float4 sets, no arrays -> no scratch).
// Rationale: SMEM shares lgkmcnt with ds_read, so per-t s_load bursts force
// coarse waits (head pinned at 74% VALU across 4 variants). VMEM is vmcnt-
// tracked -> t+1's weight loads fly under t's 128 FMAs. Cost: VGPR ~120 ->
// launch_bounds(512,4), 2 blocks/CU.
// ---------------------------------------------------------------------------

__global__ void k_count_int(const int* __restrict__ dst, int* __restrict__ cnt, int e) {
  int i = blockIdx.x * blockDim.x + threadIdx.x;
  if (i < e) atomicAdd(&cnt[dst[i]], 1);
}

__global__ void k_dinv(const int* __restrict__ cnt, float* __restrict__ dinv, int n) {
  int i = blockIdx.x * blockDim.x + threadIdx.x;
  if (i < n) dinv[i] = rsqrtf((float)cnt[i] + 1.0f);  // self-loop included
}

__global__ __launch_bounds__(256) void k_scan_block(const int* __restrict__ cnt,
                                                    int* __restrict__ rp,
                                                    int* __restrict__ bsum, int n) {
  __shared__ int wsum[4];
  int tid = threadIdx.x;
  int lane = tid & 63, w = tid >> 6;
  int idx = blockIdx.x * 1024 + tid * 4;
  int v0 = (idx + 0 < n) ? cnt[idx + 0] : 0;
  int v1 = (idx + 1 < n) ? cnt[idx + 1] : 0;
  int v2 = (idx + 2 < n) ? cnt[idx + 2] : 0;
  int v3 = (idx + 3 < n) ? cnt[idx + 3] : 0;
  int tot = v0 + v1 + v2 + v3;
  int x = tot;
#pragma unroll
  for (int off = 1; off < 64; off <<= 1) {
    int y = __shfl_up(x, off, 64);
    if (lane >= off) x += y;
  }
  if (lane == 63) wsum[w] = x;
  __syncthreads();
  int woff = 0;
  for (int i = 0; i < w; ++i) woff += wsum[i];
  int run = woff + x - tot;
  if (idx + 0 < n) rp[idx + 0] = run; run += v0;
  if (idx + 1 < n) rp[idx + 1] = run; run += v1;
  if (idx + 2 < n) rp[idx + 2] = run; run += v2;
  if (idx + 3 < n) rp[idx + 3] = run;
  if (tid == 255) bsum[blockIdx.x] = wsum[0] + wsum[1] + wsum[2] + wsum[3];
}

__global__ void k_scan_bsum(int* __restrict__ bsum, int nb) {
  int l = threadIdx.x;
  int v0 = (l < nb) ? bsum[l] : 0;
  int v1 = (64 + l < nb) ? bsum[64 + l] : 0;
  int i0 = v0;
#pragma unroll
  for (int off = 1; off < 64; off <<= 1) {
    int y = __shfl_up(i0, off, 64);
    if (l >= off) i0 += y;
  }
  int T0 = __shfl(i0, 63, 64);
  int i1 = v1;
#pragma unroll
  for (int off = 1; off < 64; off <<= 1) {
    int y = __shfl_up(i1, off, 64);
    if (l >= off) i1 += y;
  }
  if (l < nb) bsum[l] = i0 - v0;
  if (64 + l < nb) bsum[64 + l] = T0 + i1 - v1;
}

// add block offsets; also emit cursor copy for k_fill; set rp[n]=E.
__global__ void k_scan_add(int* __restrict__ rp, int* __restrict__ cur,
                           const int* __restrict__ bsum, int n, int e) {
  int i = blockIdx.x * blockDim.x + threadIdx.x;
  if (i < n) {
    int v = rp[i] + bsum[i >> 10];
    rp[i] = v;
    cur[i] = v;
  }
  if (i == 0) rp[n] = e;
}

// fill CSR buckets; also precompute per-edge coefficient.
__global__ void k_fill(const int* __restrict__ src, const int* __restrict__ dst,
                       int* __restrict__ cur, const float* __restrict__ dinv,
                       int* __restrict__ srcs, float* __restrict__ coefs, int e) {
  int i = blockIdx.x * blockDim.x + threadIdx.x;
  if (i >= e) return;
  int s = src[i], d = dst[i];
  int pos = atomicAdd(&cur[d], 1);
  srcs[pos] = s;
  coefs[pos] = dinv[s] * dinv[d];
}

// ---------------------------------------------------------------------------
// Matmul, W-in-VGPR: OUT[node][lane] = sum_k IN[node][k]*W[k][lane].
// ---------------------------------------------------------------------------
template <int K>
__global__ __launch_bounds__(256) void k_matmul_w(const float* __restrict__ IN,
                                                  const float* __restrict__ W,
                                                  float* __restrict__ OUT,
                                                  int n, int npw) {
  __shared__ float rows[4][K];
  const int wv = threadIdx.x >> 6, lane = threadIdx.x & 63;
  float wreg[K];
#pragma unroll
  for (int k = 0; k < K; ++k) wreg[k] = W[k * 64 + lane];
  int base = (blockIdx.x * 4 + wv) * npw;
  if (base >= n) return;
  int nEnd = base + npw;
  if (nEnd > n) nEnd = n;
  float p0 = IN[(size_t)base * K + lane];
  float p1 = (K == 128) ? IN[(size_t)base * K + 64 + lane] : 0.f;
  for (int node = base; node < nEnd; ++node) {
    rows[wv][lane] = p0;
    if (K == 128) rows[wv][64 + lane] = p1;
    if (node + 1 < nEnd) {  // prefetch next row under this node's compute
      p0 = IN[(size_t)(node + 1) * K + lane];
      if (K == 128) p1 = IN[(size_t)(node + 1) * K + 64 + lane];
    }
    float a0 = 0.f, a1 = 0.f, a2 = 0.f, a3 = 0.f;
#pragma unroll
    for (int k = 0; k < K; k += 4) {
      float4 xk = *(const float4*)&rows[wv][k];
      a0 = fmaf(xk.x, wreg[k + 0], a0);
      a1 = fmaf(xk.y, wreg[k + 1], a1);
      a2 = fmaf(xk.z, wreg[k + 2], a2);
      a3 = fmaf(xk.w, wreg[k + 3], a3);
    }
    OUT[(size_t)node * 64 + lane] = (a0 + a1) + (a2 + a3);
  }
}

// one wave per node; wave-uniform shfl-broadcast accumulate; coalesced
// srcs/coefs streams. 2x unroll with both row loads issued before FMAs.
__global__ void k_gather(const float* __restrict__ hlin, const int* __restrict__ rp,
                         const int* __restrict__ srcs, const float* __restrict__ coefs,
                         const float* __restrict__ dinv,
                         const float* __restrict__ bias, float* __restrict__ outB,
                         int n) {
  int warp = threadIdx.x >> 6, lane = threadIdx.x & 63;
  int node = blockIdx.x * 4 + warp;
  if (node >= n) return;
  int g = lane >> 4, l16 = lane & 15;
  int beg = rp[node], end = rp[node + 1];
  int deg = end - beg;
  float dn = dinv[node];
  float ax = 0.f, ay = 0.f, az = 0.f, aw = 0.f;
  for (int base = 0; base < deg; base += 64) {
    int rem = deg - base;
    int m = rem < 64 ? rem : 64;
    int idx = 0;
    float cf = 0.f;
    if (lane < m) {
      idx = srcs[beg + base + lane];
      cf = coefs[beg + base + lane];
    }
    int iters = (m + 3) >> 2;  // wave-uniform trip count
    int i = 0;
    for (; i + 2 <= iters; i += 2) {
      int k0 = g + 4 * i, k1 = k0 + 4;       // both <= 63
      int s0 = __shfl(idx, k0, 64);
      float c0 = __shfl(cf, k0, 64);
      int s1 = __shfl(idx, k1, 64);
      float c1 = __shfl(cf, k1, 64);
      float4 h0 = *(const float4*)(hlin + (size_t)s0 * 64 + l16 * 4);
      float4 h1 = *(const float4*)(hlin + (size_t)s1 * 64 + l16 * 4);
      ax = fmaf(h0.x, c0, ax);
      ay = fmaf(h0.y, c0, ay);
      az = fmaf(h0.z, c0, az);
      aw = fmaf(h0.w, c0, aw);
      ax = fmaf(h1.x, c1, ax);
      ay = fmaf(h1.y, c1, ay);
      az = fmaf(h1.z, c1, az);
      aw = fmaf(h1.w, c1, aw);
    }
    if (i < iters) {
      int k = g + 4 * i;
      int s = __shfl(idx, k, 64);
      float c = __shfl(cf, k, 64);
      float4 h = *(const float4*)(hlin + (size_t)s * 64 + l16 * 4);
      ax = fmaf(h.x, c, ax);
      ay = fmaf(h.y, c, ay);
      az = fmaf(h.z, c, az);
      aw = fmaf(h.w, c, aw);
    }
  }
#pragma unroll
  for (int off = 16; off < 64; off <<= 1) {
    ax += __shfl_xor(ax, off, 64);
    ay += __shfl_xor(ay, off, 64);
    az += __shfl_xor(az, off, 64);
    aw += __shfl_xor(aw, off, 64);
  }
  if (g == 0) {
    float4 hs = *(const float4*)(hlin + (size_t)node * 64 + l16 * 4);
    float4 bb = *(const float4*)(bias + l16 * 4);
    float dd = dn * dn;
    float4 o;
    o.x = ax + hs.x * dd + bb.x;
    o.y = ay + hs.y * dd + bb.y;
    o.z = az + hs.z * dd + bb.z;
    o.w = aw + hs.w * dd + bb.w;
    o.x = o.x > 0.f ? o.x : 0.f;
    o.y = o.y > 0.f ? o.y : 0.f;
    o.z = o.z > 0.f ? o.z : 0.f;
    o.w = o.w > 0.f ? o.w : 0.f;
    *(float4*)(outB + (size_t)node * 64 + l16 * 4) = o;
  }
}

// ---------------------------------------------------------------------------
// Edge head: 512 threads = 8 waves, 256 pairs/block, 4 pairs/lane.
// Wave w owns cols [8w, 8w+8); lane owns pairs 4*lane..4*lane+3.
// 4 phases x 16 rows; u[16][256]+v[16][256], parts reuse u -> 32KB LDS.
// u/v staged at 128B-line granularity (even phase loads full line + stash).
// M1 via VMEM broadcast loads, register double-buffered (sets A/B of 8
// named float4 each): body t issues loads for t+1, then runs t's 128 FMAs.
// vmcnt-tracked -> decoupled from ds_read lgkmcnt (the r3-r10 74%-VALU stall).
// ---------------------------------------------------------------------------
__global__ __launch_bounds__(512, 4) void k_edge_head(
    const float* __restrict__ H, const int* __restrict__ ep,
    const float* __restrict__ M1, const float* __restrict__ mb1,
    const float* __restrict__ M2, const float* __restrict__ mb2,
    float* __restrict__ out, int p_total) {
  __shared__ float sbuf[8192];  // u:[0,4096) v:[4096,8192); parts reuse u

  const int tid = threadIdx.x;
  const int pair0 = blockIdx.x * 256;

  const int pi = tid & 255;
  const int hf = tid >> 8;
  const int gp_pi = pair0 + pi;
  const bool valid = gp_pi < p_total;
  int node = 0;
  if (valid) node = hf ? ep[p_total + gp_pi] : ep[gp_pi];
  float* __restrict__ myb = sbuf + hf * 4096;

  const int lane = tid & 63;
  const int w = tid >> 6;
  const int cg = __builtin_amdgcn_readfirstlane(w);
  const int p0 = 4 * lane;
  const float* __restrict__ Mw = M1 + cg * 8;

  float acc[8][4];
#pragma unroll
  for (int c = 0; c < 8; ++c)
#pragma unroll
    for (int p = 0; p < 4; ++p) acc[c][p] = 0.f;

  float4 st0, st1, st2, st3;  // u/v staging stash

  // M1 weight double-buffer: u-block cols 0-3/4-7, v, |u-v|, u*v blocks.
  float4 Au0, Au1, Av0, Av1, Ad0, Ad1, Am0, Am1;
  float4 Bu0, Bu1, Bv0, Bv1, Bd0, Bd1, Bm0, Bm1;

// load weights for feature-row tt into a named set (VMEM broadcast; rows of
// the four 64x64 blocks are 1024 float4 apart).
#define LW(tt, u0, u1, v0, v1, d0, d1, m0, m1)            \
  {                                                       \
    const float4* q = (const float4*)(Mw + (tt) * 64);    \
    u0 = q[0];    u1 = q[1];                              \
    v0 = q[1024]; v1 = q[1025];                           \
    d0 = q[2048]; d1 = q[2049];                           \
    m0 = q[3072]; m1 = q[3073];                           \
  }

#define CB(c, wu, wv, wd, wm)                             \
  acc[c][0] = fmaf(uu0, wu, acc[c][0]);                   \
  acc[c][0] = fmaf(vv0, wv, acc[c][0]);                   \
  acc[c][0] = fmaf(dd0, wd, acc[c][0]);                   \
  acc[c][0] = fmaf(mm0, wm, acc[c][0]);                   \
  acc[c][1] = fmaf(uu1, wu, acc[c][1]);                   \
  acc[c][1] = fmaf(vv1, wv, acc[c][1]);                   \
  acc[c][1] = fmaf(dd1, wd, acc[c][1]);                   \
  acc[c][1] = fmaf(mm1, wm, acc[c][1]);                   \
  acc[c][2] = fmaf(uu2, wu, acc[c][2]);                   \
  acc[c][2] = fmaf(vv2, wv, acc[c][2]);                   \
  acc[c][2] = fmaf(dd2, wd, acc[c][2]);                   \
  acc[c][2] = fmaf(mm2, wm, acc[c][2]);                   \
  acc[c][3] = fmaf(uu3, wu, acc[c][3]);                   \
  acc[c][3] = fmaf(vv3, wv, acc[c][3]);                   \
  acc[c][3] = fmaf(mm3, wm, acc[c][3]);                   \
  acc[c][3] = fmaf(dd3, wd, acc[c][3]);

// GEMM body for phase-local row tloc using weight set (u0..m1).
#define GB(tloc, u0, u1, v0, v1, d0, d1, m0, m1)                      \
  {                                                                   \
    float4 U4 = *(const float4*)&sbuf[(tloc)*256 + p0];               \
    float4 V4 = *(const float4*)&sbuf[4096 + (tloc)*256 + p0];        \
    float uu0 = U4.x, uu1 = U4.y, uu2 = U4.z, uu3 = U4.w;             \
    float vv0 = V4.x, vv1 = V4.y, vv2 = V4.z, vv3 = V4.w;             \
    float dd0 = fabsf(uu0 - vv0), dd1 = fabsf(uu1 - vv1);             \
    float dd2 = fabsf(uu2 - vv2), dd3 = fabsf(uu3 - vv3);             \
    float mm0 = uu0 * vv0, mm1 = uu1 * vv1;                           \
    float mm2 = uu2 * vv2, mm3 = uu3 * vv3;                           \
    CB(0, u0.x, v0.x, d0.x, m0.x)                                     \
    CB(1, u0.y, v0.y, d0.y, m0.y)                                     \
    CB(2, u0.z, v0.z, d0.z, m0.z)                                     \
    CB(3, u0.w, v0.w, d0.w, m0.w)                                     \
    CB(4, u1.x, v1.x, d1.x, m1.x)                                     \
    CB(5, u1.y, v1.y, d1.y, m1.y)                                     \
    CB(6, u1.z, v1.z, d1.z, m1.z)                                     \
    CB(7, u1.w, v1.w, d1.w, m1.w)                                     \
  }

  // preload weights for global row 0 into set A
  LW(0, Au0, Au1, Av0, Av1, Ad0, Ad1, Am0, Am1)

#pragma unroll
  for (int ph = 0; ph < 4; ++ph) {
    if (ph) __syncthreads();  // previous phase fully consumed
    // ---- stage 16 rows of this thread's matrix (u or v), pair pi
    if (valid) {
      float4 c0, c1, c2, c3;
      if ((ph & 1) == 0) {
        const float4* hr = (const float4*)(H + (size_t)node * 64 + ph * 16);
        c0 = hr[0]; c1 = hr[1]; c2 = hr[2]; c3 = hr[3];
        st0 = hr[4]; st1 = hr[5]; st2 = hr[6]; st3 = hr[7];
      } else {
        c0 = st0; c1 = st1; c2 = st2; c3 = st3;
      }
      myb[0 * 256 + pi]  = c0.x; myb[1 * 256 + pi]  = c0.y;
      myb[2 * 256 + pi]  = c0.z; myb[3 * 256 + pi]  = c0.w;
      myb[4 * 256 + pi]  = c1.x; myb[5 * 256 + pi]  = c1.y;
      myb[6 * 256 + pi]  = c1.z; myb[7 * 256 + pi]  = c1.w;
      myb[8 * 256 + pi]  = c2.x; myb[9 * 256 + pi]  = c2.y;
      myb[10 * 256 + pi] = c2.z; myb[11 * 256 + pi] = c2.w;
      myb[12 * 256 + pi] = c3.x; myb[13 * 256 + pi] = c3.y;
      myb[14 * 256 + pi] = c3.z; myb[15 * 256 + pi] = c3.w;
    } else {
#pragma unroll
      for (int j = 0; j < 16; ++j) myb[j * 256 + pi] = 0.f;
    }
    __syncthreads();

    // ---- GEMM over this phase's 16 rows, M1 register-double-buffered
    for (int t = 0; t < 16; t += 2) {
      const int tt = ph * 16 + t;
      const int tn1 = (tt + 1) & 63;  // wrap keeps the final prefetch in-bounds
      const int tn2 = (tt + 2) & 63;
      LW(tn1, Bu0, Bu1, Bv0, Bv1, Bd0, Bd1, Bm0, Bm1)  // prefetch t+1
      GB(t, Au0, Au1, Av0, Av1, Ad0, Ad1, Am0, Am1)    // compute t
      LW(tn2, Au0, Au1, Av0, Av1, Ad0, Ad1, Am0, Am1)  // prefetch t+2
      GB(t + 1, Bu0, Bu1, Bv0, Bv1, Bd0, Bd1, Bm0, Bm1)
    }
  }
#undef LW
#undef CB
#undef GB

  __syncthreads();  // all reads of sbuf done; reuse u region for partials

  // epilogue: per pair p: part = sum_c relu(acc+mb1)*M2 over this wave's 8 cols
#pragma unroll
  for (int p = 0; p < 4; ++p) {
    float part = 0.f;
#pragma unroll
    for (int c = 0; c < 8; ++c) {
      float z = acc[c][p] + mb1[cg * 8 + c];
      z = z > 0.f ? z : 0.f;
      part = fmaf(z, M2[cg * 8 + c], part);
    }
    sbuf[w * 256 + p0 + p] = part;
  }
  __syncthreads();

  if (tid < 256) {
    int gp = pair0 + tid;
    if (gp < p_total) {
      float s = 0.f;
#pragma unroll
      for (int w8 = 0; w8 < 8; ++w8) s += sbuf[w8 * 256 + tid];
      out[gp] = s + mb2[0];
    }
  }
}

extern "C" void kernel_launch(void* const* d_in, const int* in_sizes, int n_in,
                              void* d_out, int out_size, void* d_ws, size_t ws_size,
                              hipStream_t stream) {
  const float* x   = (const float*)d_in[0];
  const int*   gei = (const int*)d_in[1];
  const int*   ep  = (const int*)d_in[2];
  const float* W1  = (const float*)d_in[3];
  const float* b1  = (const float*)d_in[4];
  const float* W2  = (const float*)d_in[5];
  const float* b2  = (const float*)d_in[6];
  const float* M1  = (const float*)d_in[7];
  const float* mb1 = (const float*)d_in[8];
  const float* M2  = (const float*)d_in[9];
  const float* mb2 = (const float*)d_in[10];
  float* out = (float*)d_out;

  const int N = in_sizes[0] / 128;
  const int E = in_sizes[1] / 2;
  const int P = in_sizes[2] / 2;
  const int* src = gei;
  const int* dst = gei + E;

  char* ws = (char*)d_ws;
  auto align256 = [](size_t b) { return (b + 255) & ~(size_t)255; };
  size_t degBytes  = align256((size_t)N * 4);
  size_t hBytes    = align256((size_t)N * 64 * 4);
  size_t cntBytes  = align256((size_t)N * 4);
  size_t rpBytes   = align256((size_t)(N + 1) * 4);
  size_t srcBytes  = align256((size_t)E * 4);

  size_t off = 0;
  float* dinv  = (float*)(ws + off); off += degBytes;
  float* A     = (float*)(ws + off); off += hBytes;    // N x 64 (hlin)
  float* B     = (float*)(ws + off); off += hBytes;    // N x 64 (h out)
  int*   cnt   = (int*)(ws + off);   off += cntBytes;  // counts -> cursors
  int*   rp    = (int*)(ws + off);   off += rpBytes;   // N+1
  int*   srcs  = (int*)(ws + off);   off += srcBytes;  // E
  float* coefs = (float*)(ws + off); off += srcBytes;  // E
  int*   bsum  = (int*)(ws + off);                     // 128

  const int BLK = 256;
  const int nb = (N + 1023) / 1024;  // scan blocks; <=128 supported (N<=131072)

  // ---- CSR build + normalization ----
  hipMemsetAsync(cnt, 0, (size_t)N * 4, stream);
  k_count_int<<<(E + BLK - 1) / BLK, BLK, 0, stream>>>(dst, cnt, E);
  k_dinv<<<(N + BLK - 1) / BLK, BLK, 0, stream>>>(cnt, dinv, N);
  k_scan_block<<<nb, BLK, 0, stream>>>(cnt, rp, bsum, N);
  k_scan_bsum<<<1, 64, 0, stream>>>(bsum, nb);
  k_scan_add<<<(N + BLK - 1) / BLK, BLK, 0, stream>>>(rp, cnt, bsum, N, E);
  k_fill<<<(E + BLK - 1) / BLK, BLK, 0, stream>>>(src, dst, cnt, dinv, srcs, coefs, E);

  const int NPW = 16;  // nodes per wave in k_matmul_w
  const int mmGrid = (N + 4 * NPW - 1) / (4 * NPW);

  // ---- layer 1 ----
  k_matmul_w<128><<<mmGrid, BLK, 0, stream>>>(x, W1, A, N, NPW);
  k_gather<<<(N + 3) / 4, BLK, 0, stream>>>(A, rp, srcs, coefs, dinv, b1, B, N);

  // ---- layer 2 ----
  k_matmul_w<64><<<mmGrid, BLK, 0, stream>>>(B, W2, A, N, NPW);
  k_gather<<<(N + 3) / 4, BLK, 0, stream>>>(A, rp, srcs, coefs, dinv, b2, B, N);

  // ---- edge head: 256 pairs per 512-thread block ----
  k_edge_head<<<(P + 255) / 256, 512, 0, stream>>>(B, ep, M1, mb1, M2, mb2, out, P);
}

// Round 13
// 460.538 us; speedup vs baseline: 1.1109x; 1.1109x over previous
//
#include <hip/hip_runtime.h>
#include <math.h>

// ---------------------------------------------------------------------------
// N2V GCN edge model, fp32.
//   CSR build: cnt=indeg(dst); dinv=rsqrt(cnt+1); rp=exscan; (src,coef) packed
//   L1: A = x@W1 ; B = relu(gatherCSR(A) + A*dinv^2 + b1)
//   L2: A = B@W2 ; B = relu(gatherCSR(A) + A*dinv^2 + b2)
//   head: per pair: feat=[u,v,|u-v|,u*v]; z=relu(feat@M1+mb1); out=z@M2+mb2
// Round-13: revert to round-10 (best, 458us). r12's VMEM-dbuf head refuted
// the lgkm theory (220us, VALU 62%): head plateau = 181us / 74% VALU across
// 6 variants. Single tweak vs r10: srcs+coefs packed into one int2 array
// (k_fill 1x8B scatter/edge instead of 2x4B; gather setup 1 load not 2).
// ---------------------------------------------------------------------------

__global__ void k_count_int(const int* __restrict__ dst, int* __restrict__ cnt, int e) {
  int i = blockIdx.x * blockDim.x + threadIdx.x;
  if (i < e) atomicAdd(&cnt[dst[i]], 1);
}

__global__ void k_dinv(const int* __restrict__ cnt, float* __restrict__ dinv, int n) {
  int i = blockIdx.x * blockDim.x + threadIdx.x;
  if (i < n) dinv[i] = rsqrtf((float)cnt[i] + 1.0f);  // self-loop included
}

__global__ __launch_bounds__(256) void k_scan_block(const int* __restrict__ cnt,
                                                    int* __restrict__ rp,
                                                    int* __restrict__ bsum, int n) {
  __shared__ int wsum[4];
  int tid = threadIdx.x;
  int lane = tid & 63, w = tid >> 6;
  int idx = blockIdx.x * 1024 + tid * 4;
  int v0 = (idx + 0 < n) ? cnt[idx + 0] : 0;
  int v1 = (idx + 1 < n) ? cnt[idx + 1] : 0;
  int v2 = (idx + 2 < n) ? cnt[idx + 2] : 0;
  int v3 = (idx + 3 < n) ? cnt[idx + 3] : 0;
  int tot = v0 + v1 + v2 + v3;
  int x = tot;
#pragma unroll
  for (int off = 1; off < 64; off <<= 1) {
    int y = __shfl_up(x, off, 64);
    if (lane >= off) x += y;
  }
  if (lane == 63) wsum[w] = x;
  __syncthreads();
  int woff = 0;
  for (int i = 0; i < w; ++i) woff += wsum[i];
  int run = woff + x - tot;
  if (idx + 0 < n) rp[idx + 0] = run; run += v0;
  if (idx + 1 < n) rp[idx + 1] = run; run += v1;
  if (idx + 2 < n) rp[idx + 2] = run; run += v2;
  if (idx + 3 < n) rp[idx + 3] = run;
  if (tid == 255) bsum[blockIdx.x] = wsum[0] + wsum[1] + wsum[2] + wsum[3];
}

__global__ void k_scan_bsum(int* __restrict__ bsum, int nb) {
  int l = threadIdx.x;
  int v0 = (l < nb) ? bsum[l] : 0;
  int v1 = (64 + l < nb) ? bsum[64 + l] : 0;
  int i0 = v0;
#pragma unroll
  for (int off = 1; off < 64; off <<= 1) {
    int y = __shfl_up(i0, off, 64);
    if (l >= off) i0 += y;
  }
  int T0 = __shfl(i0, 63, 64);
  int i1 = v1;
#pragma unroll
  for (int off = 1; off < 64; off <<= 1) {
    int y = __shfl_up(i1, off, 64);
    if (l >= off) i1 += y;
  }
  if (l < nb) bsum[l] = i0 - v0;
  if (64 + l < nb) bsum[64 + l] = T0 + i1 - v1;
}

// add block offsets; also emit cursor copy for k_fill; set rp[n]=E.
__global__ void k_scan_add(int* __restrict__ rp, int* __restrict__ cur,
                           const int* __restrict__ bsum, int n, int e) {
  int i = blockIdx.x * blockDim.x + threadIdx.x;
  if (i < n) {
    int v = rp[i] + bsum[i >> 10];
    rp[i] = v;
    cur[i] = v;
  }
  if (i == 0) rp[n] = e;
}

// fill CSR buckets; packed (src, coef) -> one 8B scattered store per edge.
__global__ void k_fill(const int* __restrict__ src, const int* __restrict__ dst,
                       int* __restrict__ cur, const float* __restrict__ dinv,
                       int2* __restrict__ sc, int e) {
  int i = blockIdx.x * blockDim.x + threadIdx.x;
  if (i >= e) return;
  int s = src[i], d = dst[i];
  int pos = atomicAdd(&cur[d], 1);
  sc[pos] = make_int2(s, __float_as_int(dinv[s] * dinv[d]));
}

// ---------------------------------------------------------------------------
// Matmul, W-in-VGPR: OUT[node][lane] = sum_k IN[node][k]*W[k][lane].
// Wave holds its W column in wreg[K] (loaded once). Node row staged per-lane
// coalesced -> LDS slice -> broadcast ds_read_b128 (4 k per read, 4 FMA each).
// Next row prefetched into regs under current node's compute.
// ---------------------------------------------------------------------------
template <int K>
__global__ __launch_bounds__(256) void k_matmul_w(const float* __restrict__ IN,
                                                  const float* __restrict__ W,
                                                  float* __restrict__ OUT,
                                                  int n, int npw) {
  __shared__ float rows[4][K];
  const int wv = threadIdx.x >> 6, lane = threadIdx.x & 63;
  float wreg[K];
#pragma unroll
  for (int k = 0; k < K; ++k) wreg[k] = W[k * 64 + lane];
  int base = (blockIdx.x * 4 + wv) * npw;
  if (base >= n) return;
  int nEnd = base + npw;
  if (nEnd > n) nEnd = n;
  float p0 = IN[(size_t)base * K + lane];
  float p1 = (K == 128) ? IN[(size_t)base * K + 64 + lane] : 0.f;
  for (int node = base; node < nEnd; ++node) {
    rows[wv][lane] = p0;
    if (K == 128) rows[wv][64 + lane] = p1;
    if (node + 1 < nEnd) {  // prefetch next row under this node's compute
      p0 = IN[(size_t)(node + 1) * K + lane];
      if (K == 128) p1 = IN[(size_t)(node + 1) * K + 64 + lane];
    }
    float a0 = 0.f, a1 = 0.f, a2 = 0.f, a3 = 0.f;
#pragma unroll
    for (int k = 0; k < K; k += 4) {
      float4 xk = *(const float4*)&rows[wv][k];
      a0 = fmaf(xk.x, wreg[k + 0], a0);
      a1 = fmaf(xk.y, wreg[k + 1], a1);
      a2 = fmaf(xk.z, wreg[k + 2], a2);
      a3 = fmaf(xk.w, wreg[k + 3], a3);
    }
    OUT[(size_t)node * 64 + lane] = (a0 + a1) + (a2 + a3);
  }
}

// one wave per node; wave-uniform shfl-broadcast accumulate; packed (src,coef)
// stream. 2x unroll with both row loads issued before FMAs -> 2 in-flight
// gathers per 16-lane group.
__global__ void k_gather(const float* __restrict__ hlin, const int* __restrict__ rp,
                         const int2* __restrict__ sc,
                         const float* __restrict__ dinv,
                         const float* __restrict__ bias, float* __restrict__ outB,
                         int n) {
  int warp = threadIdx.x >> 6, lane = threadIdx.x & 63;
  int node = blockIdx.x * 4 + warp;
  if (node >= n) return;
  int g = lane >> 4, l16 = lane & 15;
  int beg = rp[node], end = rp[node + 1];
  int deg = end - beg;
  float dn = dinv[node];
  float ax = 0.f, ay = 0.f, az = 0.f, aw = 0.f;
  for (int base = 0; base < deg; base += 64) {
    int rem = deg - base;
    int m = rem < 64 ? rem : 64;
    int idx = 0;
    float cf = 0.f;
    if (lane < m) {
      int2 p = sc[beg + base + lane];
      idx = p.x;
      cf = __int_as_float(p.y);
    }
    int iters = (m + 3) >> 2;  // wave-uniform trip count
    int i = 0;
    for (; i + 2 <= iters; i += 2) {
      int k0 = g + 4 * i, k1 = k0 + 4;       // both <= 63
      int s0 = __shfl(idx, k0, 64);
      float c0 = __shfl(cf, k0, 64);
      int s1 = __shfl(idx, k1, 64);
      float c1 = __shfl(cf, k1, 64);
      float4 h0 = *(const float4*)(hlin + (size_t)s0 * 64 + l16 * 4);
      float4 h1 = *(const float4*)(hlin + (size_t)s1 * 64 + l16 * 4);
      ax = fmaf(h0.x, c0, ax);
      ay = fmaf(h0.y, c0, ay);
      az = fmaf(h0.z, c0, az);
      aw = fmaf(h0.w, c0, aw);
      ax = fmaf(h1.x, c1, ax);
      ay = fmaf(h1.y, c1, ay);
      az = fmaf(h1.z, c1, az);
      aw = fmaf(h1.w, c1, aw);
    }
    if (i < iters) {
      int k = g + 4 * i;
      int s = __shfl(idx, k, 64);
      float c = __shfl(cf, k, 64);
      float4 h = *(const float4*)(hlin + (size_t)s * 64 + l16 * 4);
      ax = fmaf(h.x, c, ax);
      ay = fmaf(h.y, c, ay);
      az = fmaf(h.z, c, az);
      aw = fmaf(h.w, c, aw);
    }
  }
#pragma unroll
  for (int off = 16; off < 64; off <<= 1) {
    ax += __shfl_xor(ax, off, 64);
    ay += __shfl_xor(ay, off, 64);
    az += __shfl_xor(az, off, 64);
    aw += __shfl_xor(aw, off, 64);
  }
  if (g == 0) {
    float4 hs = *(const float4*)(hlin + (size_t)node * 64 + l16 * 4);
    float4 bb = *(const float4*)(bias + l16 * 4);
    float dd = dn * dn;
    float4 o;
    o.x = ax + hs.x * dd + bb.x;
    o.y = ay + hs.y * dd + bb.y;
    o.z = az + hs.z * dd + bb.z;
    o.w = aw + hs.w * dd + bb.w;
    o.x = o.x > 0.f ? o.x : 0.f;
    o.y = o.y > 0.f ? o.y : 0.f;
    o.z = o.z > 0.f ? o.z : 0.f;
    o.w = o.w > 0.f ? o.w : 0.f;
    *(float4*)(outB + (size_t)node * 64 + l16 * 4) = o;
  }
}

// ---------------------------------------------------------------------------
// Edge head (round-8/10 version, plateau 181us): 512 threads = 8 waves,
// 256 pairs/block, 4 pairs/lane. Wave w owns cols [8w, 8w+8); lane owns
// pairs 4*lane..+3. 4 phases x 16 rows; u[16][256]+v[16][256], parts reuse
// u -> 32KB LDS. Staging at 128B-line granularity: even phase loads the
// full line + reg stash; odd phase is pure LDS writes.
// ---------------------------------------------------------------------------
__global__ __launch_bounds__(512, 6) void k_edge_head(
    const float* __restrict__ H, const int* __restrict__ ep,
    const float* __restrict__ M1, const float* __restrict__ mb1,
    const float* __restrict__ M2, const float* __restrict__ mb2,
    float* __restrict__ out, int p_total) {
  __shared__ float sbuf[8192];  // u:[0,4096) v:[4096,8192); parts reuse u

  const int tid = threadIdx.x;
  const int pair0 = blockIdx.x * 256;

  const int pi = tid & 255;
  const int hf = tid >> 8;
  const int gp_pi = pair0 + pi;
  const bool valid = gp_pi < p_total;
  int node = 0;
  if (valid) node = hf ? ep[p_total + gp_pi] : ep[gp_pi];
  float* __restrict__ myb = sbuf + hf * 4096;

  const int lane = tid & 63;
  const int w = tid >> 6;
  const int cg = __builtin_amdgcn_readfirstlane(w);
  const int p0 = 4 * lane;

  float acc[8][4];
#pragma unroll
  for (int c = 0; c < 8; ++c)
#pragma unroll
    for (int p = 0; p < 4; ++p) acc[c][p] = 0.f;

  float4 st0, st1, st2, st3;  // stash: next phase's 16 rows (64B)

#pragma unroll
  for (int ph = 0; ph < 4; ++ph) {
    if (ph) __syncthreads();  // previous phase fully consumed
    if (valid) {
      float4 c0, c1, c2, c3;
      if ((ph & 1) == 0) {
        const float4* hr = (const float4*)(H + (size_t)node * 64 + ph * 16);
        c0 = hr[0]; c1 = hr[1]; c2 = hr[2]; c3 = hr[3];
        st0 = hr[4]; st1 = hr[5]; st2 = hr[6]; st3 = hr[7];
      } else {
        c0 = st0; c1 = st1; c2 = st2; c3 = st3;
      }
      myb[0 * 256 + pi]  = c0.x; myb[1 * 256 + pi]  = c0.y;
      myb[2 * 256 + pi]  = c0.z; myb[3 * 256 + pi]  = c0.w;
      myb[4 * 256 + pi]  = c1.x; myb[5 * 256 + pi]  = c1.y;
      myb[6 * 256 + pi]  = c1.z; myb[7 * 256 + pi]  = c1.w;
      myb[8 * 256 + pi]  = c2.x; myb[9 * 256 + pi]  = c2.y;
      myb[10 * 256 + pi] = c2.z; myb[11 * 256 + pi] = c2.w;
      myb[12 * 256 + pi] = c3.x; myb[13 * 256 + pi] = c3.y;
      myb[14 * 256 + pi] = c3.z; myb[15 * 256 + pi] = c3.w;
    } else {
#pragma unroll
      for (int j = 0; j < 16; ++j) myb[j * 256 + pi] = 0.f;
    }
    __syncthreads();

#pragma unroll 2
    for (int t = 0; t < 16; ++t) {
      float4 u4 = *(const float4*)&sbuf[t * 256 + p0];
      float4 v4 = *(const float4*)&sbuf[4096 + t * 256 + p0];
      float uu[4] = {u4.x, u4.y, u4.z, u4.w};
      float vv[4] = {v4.x, v4.y, v4.z, v4.w};
      float dd[4], mm[4];
#pragma unroll
      for (int p = 0; p < 4; ++p) {
        dd[p] = fabsf(uu[p] - vv[p]);
        mm[p] = uu[p] * vv[p];
      }
      const int tt = ph * 16 + t;
      const float* r0 = M1 + (size_t)tt * 64 + cg * 8;   // u block
      const float* r1 = r0 + 64 * 64;                    // v block
      const float* r2 = r0 + 128 * 64;                   // |u-v| block
      const float* r3 = r0 + 192 * 64;                   // u*v block
#pragma unroll
      for (int c = 0; c < 8; ++c) {
        float w0 = r0[c], w1 = r1[c], w2 = r2[c], w3 = r3[c];
#pragma unroll
        for (int p = 0; p < 4; ++p) {
          acc[c][p] = fmaf(uu[p], w0, acc[c][p]);
          acc[c][p] = fmaf(vv[p], w1, acc[c][p]);
          acc[c][p] = fmaf(dd[p], w2, acc[c][p]);
          acc[c][p] = fmaf(mm[p], w3, acc[c][p]);
        }
      }
    }
  }

  __syncthreads();  // all reads of sbuf done; reuse u region for partials

#pragma unroll
  for (int p = 0; p < 4; ++p) {
    float part = 0.f;
#pragma unroll
    for (int c = 0; c < 8; ++c) {
      float z = acc[c][p] + mb1[cg * 8 + c];
      z = z > 0.f ? z : 0.f;
      part = fmaf(z, M2[cg * 8 + c], part);
    }
    sbuf[w * 256 + p0 + p] = part;
  }
  __syncthreads();

  if (tid < 256) {
    int gp = pair0 + tid;
    if (gp < p_total) {
      float s = 0.f;
#pragma unroll
      for (int w8 = 0; w8 < 8; ++w8) s += sbuf[w8 * 256 + tid];
      out[gp] = s + mb2[0];
    }
  }
}

extern "C" void kernel_launch(void* const* d_in, const int* in_sizes, int n_in,
                              void* d_out, int out_size, void* d_ws, size_t ws_size,
                              hipStream_t stream) {
  const float* x   = (const float*)d_in[0];
  const int*   gei = (const int*)d_in[1];
  const int*   ep  = (const int*)d_in[2];
  const float* W1  = (const float*)d_in[3];
  const float* b1  = (const float*)d_in[4];
  const float* W2  = (const float*)d_in[5];
  const float* b2  = (const float*)d_in[6];
  const float* M1  = (const float*)d_in[7];
  const float* mb1 = (const float*)d_in[8];
  const float* M2  = (const float*)d_in[9];
  const float* mb2 = (const float*)d_in[10];
  float* out = (float*)d_out;

  const int N = in_sizes[0] / 128;
  const int E = in_sizes[1] / 2;
  const int P = in_sizes[2] / 2;
  const int* src = gei;
  const int* dst = gei + E;

  char* ws = (char*)d_ws;
  auto align256 = [](size_t b) { return (b + 255) & ~(size_t)255; };
  size_t degBytes  = align256((size_t)N * 4);
  size_t hBytes    = align256((size_t)N * 64 * 4);
  size_t cntBytes  = align256((size_t)N * 4);
  size_t rpBytes   = align256((size_t)(N + 1) * 4);
  size_t scBytes   = align256((size_t)E * 8);  // packed (src, coef)

  size_t off = 0;
  float* dinv = (float*)(ws + off); off += degBytes;
  float* A    = (float*)(ws + off); off += hBytes;    // N x 64 (hlin)
  float* B    = (float*)(ws + off); off += hBytes;    // N x 64 (h out)
  int*   cnt  = (int*)(ws + off);   off += cntBytes;  // counts -> cursors
  int*   rp   = (int*)(ws + off);   off += rpBytes;   // N+1
  int2*  sc   = (int2*)(ws + off);  off += scBytes;   // E packed (src, coef)
  int*   bsum = (int*)(ws + off);                     // 128

  const int BLK = 256;
  const int nb = (N + 1023) / 1024;  // scan blocks; <=128 supported (N<=131072)

  // ---- CSR build + normalization ----
  hipMemsetAsync(cnt, 0, (size_t)N * 4, stream);
  k_count_int<<<(E + BLK - 1) / BLK, BLK, 0, stream>>>(dst, cnt, E);
  k_dinv<<<(N + BLK - 1) / BLK, BLK, 0, stream>>>(cnt, dinv, N);
  k_scan_block<<<nb, BLK, 0, stream>>>(cnt, rp, bsum, N);
  k_scan_bsum<<<1, 64, 0, stream>>>(bsum, nb);
  k_scan_add<<<(N + BLK - 1) / BLK, BLK, 0, stream>>>(rp, cnt, bsum, N, E);
  k_fill<<<(E + BLK - 1) / BLK, BLK, 0, stream>>>(src, dst, cnt, dinv, sc, E);

  const int NPW = 16;  // nodes per wave in k_matmul_w
  const int mmGrid = (N + 4 * NPW - 1) / (4 * NPW);

  // ---- layer 1 ----
  k_matmul_w<128><<<mmGrid, BLK, 0, stream>>>(x, W1, A, N, NPW);
  k_gather<<<(N + 3) / 4, BLK, 0, stream>>>(A, rp, sc, dinv, b1, B, N);

  // ---- layer 2 ----
  k_matmul_w<64><<<mmGrid, BLK, 0, stream>>>(B, W2, A, N, NPW);
  k_gather<<<(N + 3) / 4, BLK, 0, stream>>>(A, rp, sc, dinv, b2, B, N);

  // ---- edge head: 256 pairs per 512-thread block ----
  k_edge_head<<<(P + 255) / 256, 512, 0, stream>>>(B, ep, M1, mb1, M2, mb2, out, P);
}